// Round 1
// baseline (470.958 us; speedup 1.0000x reference)
//
#include <hip/hip_runtime.h>
#include <math.h>

// Sizes (fixed by the reference)
// N=2000, M=32, H=64, EMB=32, F=32, T=12, B=4, HOR=12, K=2, L_SAGE=2, DILS=(1,2)

// ---------------- Kernel A: node MLP -> q, ek (= e@w_k), node_hidden ----------
// wave per node, lane = output feature
__global__ __launch_bounds__(256) void k_embed(
    const float* __restrict__ nf,
    const float* __restrict__ w3, const float* __restrict__ b3,
    const float* __restrict__ w4, const float* __restrict__ b4,
    const float* __restrict__ w5, const float* __restrict__ b5,
    const float* __restrict__ wq, const float* __restrict__ wk,
    const float* __restrict__ wn, const float* __restrict__ bn,
    float* __restrict__ qo, float* __restrict__ eko, float* __restrict__ nho)
{
    const int lane = threadIdx.x & 63;
    const int n = blockIdx.x * 4 + (threadIdx.x >> 6);   // 500 blocks * 4 waves = 2000

    float nfv = 0.f;
    if (lane < 32) nfv = nf[n * 32 + lane];

    // e1 = relu(nf @ w_fc3 + b3)   (32 -> 64)
    float e1 = b3[lane];
#pragma unroll
    for (int f = 0; f < 32; ++f)
        e1 = fmaf(__shfl(nfv, f), w3[f * 64 + lane], e1);
    e1 = fmaxf(e1, 0.f);

    // e2 = relu(e1 @ w_fc4 + b4)   (64 -> 64)
    float e2 = b4[lane];
#pragma unroll
    for (int f = 0; f < 64; ++f)
        e2 = fmaf(__shfl(e1, f), w4[f * 64 + lane], e2);
    e2 = fmaxf(e2, 0.f);

    // e = e2 @ w_fc5 + b5          (64 -> 32); lanes >=32 duplicate lanes 0..31
    const int c = lane & 31;
    float ev = b5[c];
#pragma unroll
    for (int f = 0; f < 64; ++f)
        ev = fmaf(__shfl(e2, f), w5[f * 32 + c], ev);

    // q = e@w_q ; ek = e@w_k ; nh = e@w_nhp + b_nhp   (32 -> 64 each)
    float qv = 0.f, ekv = 0.f, nhv = bn[lane];
#pragma unroll
    for (int f = 0; f < 32; ++f) {
        float e = __shfl(ev, f);
        qv  = fmaf(e, wq[f * 64 + lane], qv);
        ekv = fmaf(e, wk[f * 64 + lane], ekv);
        nhv = fmaf(e, wn[f * 64 + lane], nhv);
    }
    qo [n * 64 + lane] = qv;
    eko[n * 64 + lane] = ekv;
    nho[n * 64 + lane] = nhv;
}

// ---------------- Kernel B: attention scores + softmax -> w_adj ----------
// thread = (node, m); softmax across each 32-lane group
__global__ __launch_bounds__(256) void k_scores(
    const float* __restrict__ q, const float* __restrict__ ek,
    const int* __restrict__ nidx, float* __restrict__ wadj)
{
    const int tid = threadIdx.x;
    const int m = tid & 31;
    const int n = blockIdx.x * 8 + (tid >> 5);           // 250 blocks * 8 nodes
    const int j = nidx[n * 32 + m];
    const float4* qr = (const float4*)(q + n * 64);
    const float4* er = (const float4*)(ek + j * 64);
    float s = 0.f;
#pragma unroll
    for (int u = 0; u < 16; ++u) {
        float4 a = qr[u], b = er[u];
        s = fmaf(a.x, b.x, s); s = fmaf(a.y, b.y, s);
        s = fmaf(a.z, b.z, s); s = fmaf(a.w, b.w, s);
    }
    s *= 0.125f;                                          // / sqrt(64)
    float mx = s;
#pragma unroll
    for (int d = 16; d >= 1; d >>= 1) mx = fmaxf(mx, __shfl_xor(mx, d));
    const float ex = expf(s - mx);
    float sum = ex;
#pragma unroll
    for (int d = 16; d >= 1; d >>= 1) sum += __shfl_xor(sum, d);
    wadj[n * 32 + m] = ex / sum;
}

// ---------------- Kernel D: one SAGE layer ----------
// wave per (bt, n), lane = feature. FUSE: input h0 computed on the fly from
// inputs/w_in/b_in/node_hidden (saves materializing h0).
template<bool FUSE>
__global__ __launch_bounds__(256) void k_sage(
    const float* __restrict__ hin,
    const float* __restrict__ xin,   // inputs (T,B,N) when FUSE
    const float* __restrict__ w_in, const float* __restrict__ b_in,
    const float* __restrict__ nh,
    const int*   __restrict__ nidx, const float* __restrict__ wadj,
    const float* __restrict__ wself, const float* __restrict__ bself,
    const float* __restrict__ wneigh, const float* __restrict__ bneigh,
    float* __restrict__ hout)
{
    __shared__ __align__(16) float sw[64 * 64 * 2];      // [k][h][{self,neigh}]
    __shared__ __align__(16) float sv[4][64][2];         // per-wave {self,agg} vectors
    const int tid = threadIdx.x;
    for (int u = tid; u < 4096; u += 256) {
        sw[u * 2]     = wself[u];
        sw[u * 2 + 1] = wneigh[u];
    }
    __syncthreads();

    const int lane = tid & 63, wave = tid >> 6;
    const int n = blockIdx.x * 4 + wave;                 // 500 * 4 = 2000
    const int bt = blockIdx.y;                           // 0..47
    const int b = bt / 12, t = bt % 12;
    const int base = bt * 128000;                        // bt * N * H

    int   idxm = 0; float wm = 0.f, xm = 0.f;
    if (lane < 32) {
        idxm = nidx[n * 32 + lane];
        wm   = wadj[n * 32 + lane];
        if (FUSE) xm = xin[t * 8000 + b * 2000 + idxm];
    }
    float win_h = 0.f, bin_h = 0.f;
    if (FUSE) { win_h = w_in[lane]; bin_h = b_in[lane]; }

    float agg = 0.f;
#pragma unroll
    for (int m = 0; m < 32; ++m) {
        const int   j = __shfl(idxm, m);
        const float w = __shfl(wm, m);
        float v;
        if (FUSE) {
            const float xi = __shfl(xm, m);
            v = fmaf(xi, win_h, bin_h) + nh[j * 64 + lane];
        } else {
            v = hin[base + j * 64 + lane];
        }
        agg = fmaf(w, v, agg);
    }
    float self;
    if (FUSE) {
        const float xi = xin[t * 8000 + b * 2000 + n];
        self = fmaf(xi, win_h, bin_h) + nh[n * 64 + lane];
    } else {
        self = hin[base + n * 64 + lane];
    }
    sv[wave][lane][0] = self;
    sv[wave][lane][1] = agg;
    __syncthreads();                                     // uniform across block

    float acc = bself[lane] + bneigh[lane];
#pragma unroll
    for (int k = 0; k < 64; ++k) {
        const float2 sa = *(const float2*)&sv[wave][k][0];   // broadcast
        const float2 w2 = *(const float2*)&sw[(k * 64 + lane) * 2];
        acc = fmaf(sa.x, w2.x, fmaf(sa.y, w2.y, acc));
    }
    hout[base + n * 64 + lane] = fmaxf(acc, 0.f);
}

// ---------------- Kernel E: TCN (2 layers x 2 causal convs, K=2) + head ----------
template<int D>
__device__ __forceinline__ void conv_k2(const float* xls, const float* wls,
                                        float bias, float* acc, int lane)
{
#pragma unroll
    for (int t = 0; t < 12; ++t) acc[t] = bias;
#pragma unroll
    for (int i = 0; i < 64; ++i) {
        const float4 xa = *(const float4*)(xls + i * 12);
        const float4 xb = *(const float4*)(xls + i * 12 + 4);
        const float4 xc = *(const float4*)(xls + i * 12 + 8);
        const float xv[12] = {xa.x, xa.y, xa.z, xa.w, xb.x, xb.y, xb.z, xb.w,
                              xc.x, xc.y, xc.z, xc.w};
        const float2 w2 = *(const float2*)(wls + (i * 64 + lane) * 2); // {k0,k1}
#pragma unroll
        for (int t = 0; t < 12; ++t) {
            float s = fmaf(w2.y, xv[t], acc[t]);          // k=1 tap: x[t]
            if (t >= D) s = fmaf(w2.x, xv[t - D], s);     // k=0 tap: x[t-D], zero-pad
            acc[t] = s;
        }
    }
#pragma unroll
    for (int t = 0; t < 12; ++t) acc[t] = fmaxf(acc[t], 0.f);
}

template<int D>
__device__ __forceinline__ void tcn_layer(float* xls, float* wls, int tid, int lane,
    const float* W1, const float* B1, const float* W2, const float* B2, float* r)
{
    __syncthreads();   // all waves done reading previous wls contents
    for (int u = tid; u < 4096; u += 256)
        *(float2*)(wls + u * 2) = *(const float2*)(W1 + ((u & 63) * 128 + (u >> 6) * 2));
    __syncthreads();
    float y[12];
    conv_k2<D>(xls, wls, B1[lane], y, lane);
#pragma unroll
    for (int j = 0; j < 3; ++j)
        *(float4*)(xls + lane * 12 + j * 4) =
            make_float4(y[j*4], y[j*4+1], y[j*4+2], y[j*4+3]);
    __syncthreads();
    for (int u = tid; u < 4096; u += 256)
        *(float2*)(wls + u * 2) = *(const float2*)(W2 + ((u & 63) * 128 + (u >> 6) * 2));
    __syncthreads();
    conv_k2<D>(xls, wls, B2[lane], y, lane);
#pragma unroll
    for (int t = 0; t < 12; ++t) r[t] = fmaxf(y[t] + r[t], 0.f);   // residual + relu
#pragma unroll
    for (int j = 0; j < 3; ++j)
        *(float4*)(xls + lane * 12 + j * 4) =
            make_float4(r[j*4], r[j*4+1], r[j*4+2], r[j*4+3]);
}

__global__ __launch_bounds__(256) void k_tcn(
    const float* __restrict__ mid,
    const float* __restrict__ tw1, const float* __restrict__ tb1,
    const float* __restrict__ tw2, const float* __restrict__ tb2,
    const float* __restrict__ wgate, const float* __restrict__ bgate,
    const float* __restrict__ wout, const float* __restrict__ bout,
    float* __restrict__ outp)
{
    __shared__ __align__(16) float xls_all[4][768];      // [wave][i*12+t], 48B rows
    __shared__ __align__(16) float wls[8192];            // [i][o][k] interleaved
    const int tid = threadIdx.x, lane = tid & 63, wave = tid >> 6;
    const int n = blockIdx.x * 4 + wave, b = blockIdx.y; // 500 x 4 grid
    float* xls = xls_all[wave];

    float r[12];
#pragma unroll
    for (int t = 0; t < 12; ++t)
        r[t] = mid[((b * 12 + t) * 2000 + n) * 64 + lane];
#pragma unroll
    for (int j = 0; j < 3; ++j)
        *(float4*)(xls + lane * 12 + j * 4) =
            make_float4(r[j*4], r[j*4+1], r[j*4+2], r[j*4+3]);
    const float h_s = r[11];                             // mid_output[:, -1]

    tcn_layer<1>(xls, wls, tid, lane, tw1,        tb1,      tw2,        tb2,      r);
    tcn_layer<2>(xls, wls, tid, lane, tw1 + 8192, tb1 + 64, tw2 + 8192, tb2 + 64, r);

    const float h_t = r[11];
    float p = h_t * wgate[lane];
#pragma unroll
    for (int d = 1; d < 64; d <<= 1) p += __shfl_xor(p, d);
    const float gate = 1.f / (1.f + expf(-(p + bgate[0])));
    const float fo = gate * h_t + (1.f - gate) * h_s;
    xls[lane] = fo;
    if (lane < 12) {
        float acc = bout[lane];
#pragma unroll
        for (int o = 0; o < 64; ++o)
            acc = fmaf(xls[o], wout[o * 12 + lane], acc);
        outp[lane * 8000 + b * 2000 + n] = acc;          // (HOR,B,N)
    }
}

extern "C" void kernel_launch(void* const* d_in, const int* in_sizes, int n_in,
                              void* d_out, int out_size, void* d_ws, size_t ws_size,
                              hipStream_t stream) {
    const float* inputs     = (const float*)d_in[0];
    const float* node_feas  = (const float*)d_in[1];
    const int*   node_index = (const int*)  d_in[2];
    const float* w_fc3 = (const float*)d_in[3];
    const float* b_fc3 = (const float*)d_in[4];
    const float* w_fc4 = (const float*)d_in[5];
    const float* b_fc4 = (const float*)d_in[6];
    const float* w_fc5 = (const float*)d_in[7];
    const float* b_fc5 = (const float*)d_in[8];
    const float* w_nhp = (const float*)d_in[9];
    const float* b_nhp = (const float*)d_in[10];
    const float* w_q   = (const float*)d_in[11];
    const float* w_k   = (const float*)d_in[12];
    const float* w_in  = (const float*)d_in[13];
    const float* b_in  = (const float*)d_in[14];
    const float* sws   = (const float*)d_in[15];
    const float* sbs   = (const float*)d_in[16];
    const float* swn   = (const float*)d_in[17];
    const float* sbn   = (const float*)d_in[18];
    const float* tw1   = (const float*)d_in[19];
    const float* tb1   = (const float*)d_in[20];
    const float* tw2   = (const float*)d_in[21];
    const float* tb2   = (const float*)d_in[22];
    const float* wgate = (const float*)d_in[23];
    const float* bgate = (const float*)d_in[24];
    const float* wout  = (const float*)d_in[25];
    const float* bout  = (const float*)d_in[26];

    float* out  = (float*)d_out;           // (12,4,2000)        96000
    float* mid  = out + 96000;             // (4,12,2000,64)     6144000
    float* wadj = mid + 6144000;           // (2000,32)          64000

    float* q  = (float*)d_ws;              // 2000*64
    float* ek = q  + 128000;               // 2000*64
    float* nh = ek + 128000;               // 2000*64
    float* h1 = nh + 128000;               // 48*2000*64

    k_embed<<<500, 256, 0, stream>>>(node_feas, w_fc3, b_fc3, w_fc4, b_fc4,
                                     w_fc5, b_fc5, w_q, w_k, w_nhp, b_nhp,
                                     q, ek, nh);
    k_scores<<<250, 256, 0, stream>>>(q, ek, node_index, wadj);

    dim3 gs(500, 48);
    k_sage<true><<<gs, 256, 0, stream>>>(nullptr, inputs, w_in, b_in, nh,
        node_index, wadj, sws, sbs, swn, sbn, h1);
    k_sage<false><<<gs, 256, 0, stream>>>(h1, nullptr, nullptr, nullptr, nullptr,
        node_index, wadj, sws + 4096, sbs + 64, swn + 4096, sbn + 64, mid);

    dim3 gt(500, 4);
    k_tcn<<<gt, 256, 0, stream>>>(mid, tw1, tb1, tw2, tb2,
                                  wgate, bgate, wout, bout, out);
}

// Round 2
// 215.136 us; speedup vs baseline: 2.1891x; 2.1891x over previous
//
#include <hip/hip_runtime.h>
#include <math.h>

// Sizes: N=2000, M=32, H=64, EMB=32, F=32, T=12, B=4, HOR=12, K=2, DILS=(1,2)

// ---------------- K1: node MLP -> q, ek, nh2 (= e@w_nhp + b_nhp + b_in); also xT ----
__global__ __launch_bounds__(256) void k_embed(
    const float* __restrict__ nf, const float* __restrict__ inputs,
    const float* __restrict__ w3, const float* __restrict__ b3,
    const float* __restrict__ w4, const float* __restrict__ b4,
    const float* __restrict__ w5, const float* __restrict__ b5,
    const float* __restrict__ wq, const float* __restrict__ wk,
    const float* __restrict__ wn, const float* __restrict__ bn,
    const float* __restrict__ b_in,
    float* __restrict__ qo, float* __restrict__ eko, float* __restrict__ nho,
    float* __restrict__ xT)
{
    const int tid = threadIdx.x;
    if (tid < 192) {                                   // xT transpose: 500*192 = 96000
        const int id = blockIdx.x * 192 + tid;
        const int t = id / 8000, rem = id % 8000;
        const int b = rem / 2000, n2 = rem % 2000;
        xT[n2 * 48 + b * 12 + t] = inputs[id];
    }
    const int lane = tid & 63;
    const int n = blockIdx.x * 4 + (tid >> 6);

    float nfv = 0.f;
    if (lane < 32) nfv = nf[n * 32 + lane];

    float e1 = b3[lane];
#pragma unroll
    for (int f = 0; f < 32; ++f)
        e1 = fmaf(__shfl(nfv, f), w3[f * 64 + lane], e1);
    e1 = fmaxf(e1, 0.f);

    float e2 = b4[lane];
#pragma unroll
    for (int f = 0; f < 64; ++f)
        e2 = fmaf(__shfl(e1, f), w4[f * 64 + lane], e2);
    e2 = fmaxf(e2, 0.f);

    const int c = lane & 31;
    float ev = b5[c];
#pragma unroll
    for (int f = 0; f < 64; ++f)
        ev = fmaf(__shfl(e2, f), w5[f * 32 + c], ev);

    float qv = 0.f, ekv = 0.f, nhv = bn[lane] + b_in[lane];
#pragma unroll
    for (int f = 0; f < 32; ++f) {
        float e = __shfl(ev, f);
        qv  = fmaf(e, wq[f * 64 + lane], qv);
        ekv = fmaf(e, wk[f * 64 + lane], ekv);
        nhv = fmaf(e, wn[f * 64 + lane], nhv);
    }
    qo [n * 64 + lane] = qv;
    eko[n * 64 + lane] = ekv;
    nho[n * 64 + lane] = nhv;
}

// ---------------- K2: attention scores + softmax -> w_adj ----------
__global__ __launch_bounds__(256) void k_scores(
    const float* __restrict__ q, const float* __restrict__ ek,
    const int* __restrict__ nidx, float* __restrict__ wadj)
{
    const int tid = threadIdx.x;
    const int m = tid & 31;
    const int n = blockIdx.x * 8 + (tid >> 5);
    const int j = nidx[n * 32 + m];
    const float4* qr = (const float4*)(q + n * 64);
    const float4* er = (const float4*)(ek + j * 64);
    float s = 0.f;
#pragma unroll
    for (int u = 0; u < 16; ++u) {
        float4 a = qr[u], b = er[u];
        s = fmaf(a.x, b.x, s); s = fmaf(a.y, b.y, s);
        s = fmaf(a.z, b.z, s); s = fmaf(a.w, b.w, s);
    }
    s *= 0.125f;
    float mx = s;
#pragma unroll
    for (int d = 16; d >= 1; d >>= 1) mx = fmaxf(mx, __shfl_xor(mx, d));
    const float ex = expf(s - mx);
    float sum = ex;
#pragma unroll
    for (int d = 16; d >= 1; d >>= 1) sum += __shfl_xor(sum, d);
    wadj[n * 32 + m] = ex / sum;
}

// ---------------- K3: ax[n][bt] = sum_m w[n,m] * x[bt, j_m];  pack xa = {x_self, ax} ----
__global__ __launch_bounds__(256) void k_ax(
    const float* __restrict__ xT, const int* __restrict__ nidx,
    const float* __restrict__ wadj, float2* __restrict__ xa)
{
    const int lane = threadIdx.x & 63, wave = threadIdx.x >> 6;
    const int n = blockIdx.x * 4 + wave;
    int j = 0; float w = 0.f;
    if (lane < 32) { j = nidx[n * 32 + lane]; w = wadj[n * 32 + lane]; }
    const bool act = lane < 48;
    float ax = 0.f;
#pragma unroll
    for (int m = 0; m < 32; ++m) {
        const int jm = __shfl(j, m);
        const float wm = __shfl(w, m);
        const float xv = act ? xT[jm * 48 + lane] : 0.f;
        ax = fmaf(wm, xv, ax);
    }
    if (act) xa[n * 48 + lane] = make_float2(xT[n * 48 + lane], ax);
}

// ---------------- K3b: base1[n] = nh2[n]@Ws1 + (A nh2)[n]@Wn1 + b1 ; block 500: vecs ----
__global__ __launch_bounds__(256) void k_prep(
    const float* __restrict__ nh2, const int* __restrict__ nidx,
    const float* __restrict__ wadj,
    const float* __restrict__ sws, const float* __restrict__ sbs,
    const float* __restrict__ swn, const float* __restrict__ sbn,
    const float* __restrict__ w_in,
    float* __restrict__ base1, float* __restrict__ vecs)
{
    const int tid = threadIdx.x;
    const int lane = tid & 63, wave = tid >> 6;
    if (blockIdx.x == 500) {                      // s1v = w_in@Ws1, n1v = w_in@Wn1
        if (wave == 0) {
            const float wv = w_in[lane];
            float s1 = 0.f, n1 = 0.f;
#pragma unroll
            for (int k = 0; k < 64; ++k) {
                const float wkk = __shfl(wv, k);
                s1 = fmaf(wkk, sws[k * 64 + lane], s1);
                n1 = fmaf(wkk, swn[k * 64 + lane], n1);
            }
            vecs[lane] = s1; vecs[64 + lane] = n1;
        }
        return;
    }
    __shared__ float2 sw1[4096];
    __shared__ float2 sv1[4][64];
    for (int u = tid; u < 4096; u += 256)
        sw1[u] = make_float2(sws[u], swn[u]);
    __syncthreads();
    const int n = blockIdx.x * 4 + wave;
    int jv = 0; float wv = 0.f;
    if (lane < 32) { jv = nidx[n * 32 + lane]; wv = wadj[n * 32 + lane]; }
    const float self = nh2[n * 64 + lane];
    float anh = 0.f;
#pragma unroll
    for (int m = 0; m < 32; ++m) {
        const int jm = __shfl(jv, m);
        const float wm = __shfl(wv, m);
        anh = fmaf(wm, nh2[jm * 64 + lane], anh);
    }
    sv1[wave][lane] = make_float2(self, anh);
    float acc = sbs[lane] + sbn[lane];
#pragma unroll
    for (int k = 0; k < 64; ++k) {
        const float2 sa = sv1[wave][k];            // broadcast
        const float2 w2 = sw1[k * 64 + lane];
        acc = fmaf(sa.x, w2.x, fmaf(sa.y, w2.y, acc));
    }
    base1[n * 64 + lane] = acc;
}

// ---------------- K4: fused SAGE layer 2 (recompute h1 from scalars) -> mid ----------
// block = node n, 8 waves x 6 bt each. h1[bt,j,:] = relu(x*s1v + ax*n1v + base1_j)
__global__ __launch_bounds__(512, 4) void k_sage2(
    const float* __restrict__ base1, const float2* __restrict__ xa,
    const float* __restrict__ vecs,
    const int* __restrict__ nidx, const float* __restrict__ wadj,
    const float* __restrict__ sws, const float* __restrict__ sbs,
    const float* __restrict__ swn, const float* __restrict__ sbn,
    float* __restrict__ mid)
{
    __shared__ float2 sw2[4096];                  // {Ws2,Wn2}[k*64+h], 32 KB
    __shared__ float2 sv[48][64];                 // {h1self, agg}[bt][k], 24 KB
    __shared__ int2 jwl[32];                      // {j, bits(w)}
    const int tid = threadIdx.x, lane = tid & 63, wave = tid >> 6;
    const int n = blockIdx.x;
    if (tid < 32)
        jwl[tid] = make_int2(nidx[n * 32 + tid], __float_as_int(wadj[n * 32 + tid]));
    for (int u = tid; u < 4096; u += 512)
        sw2[u] = make_float2(sws[4096 + u], swn[4096 + u]);
    __syncthreads();

    const float s1 = vecs[lane], n1 = vecs[64 + lane];
    const float bs = base1[n * 64 + lane];
    const float b2 = sbs[64 + lane] + sbn[64 + lane];
    const int bt0 = wave * 6;

    float agg[6] = {0.f, 0.f, 0.f, 0.f, 0.f, 0.f};
#pragma unroll 8
    for (int m = 0; m < 32; ++m) {
        const int2 jw = jwl[m];
        const int j = jw.x;
        const float w = __int_as_float(jw.y);
        const float bj = base1[j * 64 + lane];    // wave-wide 256B, L2-hot
        const float2* xr = xa + j * 48 + bt0;     // uniform 8B loads
#pragma unroll
        for (int r = 0; r < 6; ++r) {
            const float2 v = xr[r];
            const float t = fmaf(v.x, s1, fmaf(v.y, n1, bj));
            agg[r] = fmaf(w, fmaxf(t, 0.f), agg[r]);
        }
    }
#pragma unroll
    for (int r = 0; r < 6; ++r) {
        const float2 v = xa[n * 48 + bt0 + r];
        const float h1s = fmaxf(fmaf(v.x, s1, fmaf(v.y, n1, bs)), 0.f);
        sv[bt0 + r][lane] = make_float2(h1s, agg[r]);
    }
    float acc[6];
#pragma unroll
    for (int r = 0; r < 6; ++r) acc[r] = b2;
#pragma unroll
    for (int k = 0; k < 64; ++k) {
        const float2 w2 = sw2[k * 64 + lane];     // 2-way bank alias: free
#pragma unroll
        for (int r = 0; r < 6; ++r) {
            const float2 ha = sv[bt0 + r][k];     // broadcast
            acc[r] = fmaf(ha.x, w2.x, fmaf(ha.y, w2.y, acc[r]));
        }
    }
#pragma unroll
    for (int r = 0; r < 6; ++r)
        mid[((bt0 + r) * 2000 + n) * 64 + lane] = fmaxf(acc[r], 0.f);
}

// ---------------- K5: TCN (2 layers x 2 causal convs, K=2) + head ----------
template<int D>
__device__ __forceinline__ void conv_k2(const float* xls, const float* wls,
                                        float bias, float* acc, int lane)
{
#pragma unroll
    for (int t = 0; t < 12; ++t) acc[t] = bias;
#pragma unroll
    for (int i = 0; i < 64; ++i) {
        const float4 xa = *(const float4*)(xls + i * 12);
        const float4 xb = *(const float4*)(xls + i * 12 + 4);
        const float4 xc = *(const float4*)(xls + i * 12 + 8);
        const float xv[12] = {xa.x, xa.y, xa.z, xa.w, xb.x, xb.y, xb.z, xb.w,
                              xc.x, xc.y, xc.z, xc.w};
        const float2 w2 = *(const float2*)(wls + (i * 64 + lane) * 2);
#pragma unroll
        for (int t = 0; t < 12; ++t) {
            float s = fmaf(w2.y, xv[t], acc[t]);
            if (t >= D) s = fmaf(w2.x, xv[t - D], s);
            acc[t] = s;
        }
    }
#pragma unroll
    for (int t = 0; t < 12; ++t) acc[t] = fmaxf(acc[t], 0.f);
}

template<int D>
__device__ __forceinline__ void tcn_layer(float* xls, float* wls, int tid, int lane,
    const float* W1, const float* B1, const float* W2, const float* B2, float* r)
{
    __syncthreads();
    for (int u = tid; u < 4096; u += 256)
        *(float2*)(wls + u * 2) = *(const float2*)(W1 + ((u & 63) * 128 + (u >> 6) * 2));
    __syncthreads();
    float y[12];
    conv_k2<D>(xls, wls, B1[lane], y, lane);
#pragma unroll
    for (int j = 0; j < 3; ++j)
        *(float4*)(xls + lane * 12 + j * 4) =
            make_float4(y[j*4], y[j*4+1], y[j*4+2], y[j*4+3]);
    __syncthreads();
    for (int u = tid; u < 4096; u += 256)
        *(float2*)(wls + u * 2) = *(const float2*)(W2 + ((u & 63) * 128 + (u >> 6) * 2));
    __syncthreads();
    conv_k2<D>(xls, wls, B2[lane], y, lane);
#pragma unroll
    for (int t = 0; t < 12; ++t) r[t] = fmaxf(y[t] + r[t], 0.f);
#pragma unroll
    for (int j = 0; j < 3; ++j)
        *(float4*)(xls + lane * 12 + j * 4) =
            make_float4(r[j*4], r[j*4+1], r[j*4+2], r[j*4+3]);
}

__global__ __launch_bounds__(256) void k_tcn(
    const float* __restrict__ mid,
    const float* __restrict__ tw1, const float* __restrict__ tb1,
    const float* __restrict__ tw2, const float* __restrict__ tb2,
    const float* __restrict__ wgate, const float* __restrict__ bgate,
    const float* __restrict__ wout, const float* __restrict__ bout,
    float* __restrict__ outp)
{
    __shared__ __align__(16) float xls_all[4][768];
    __shared__ __align__(16) float wls[8192];
    const int tid = threadIdx.x, lane = tid & 63, wave = tid >> 6;
    const int n = blockIdx.x * 4 + wave, b = blockIdx.y;
    float* xls = xls_all[wave];

    float r[12];
#pragma unroll
    for (int t = 0; t < 12; ++t)
        r[t] = mid[((b * 12 + t) * 2000 + n) * 64 + lane];
#pragma unroll
    for (int j = 0; j < 3; ++j)
        *(float4*)(xls + lane * 12 + j * 4) =
            make_float4(r[j*4], r[j*4+1], r[j*4+2], r[j*4+3]);
    const float h_s = r[11];

    tcn_layer<1>(xls, wls, tid, lane, tw1,        tb1,      tw2,        tb2,      r);
    tcn_layer<2>(xls, wls, tid, lane, tw1 + 8192, tb1 + 64, tw2 + 8192, tb2 + 64, r);

    const float h_t = r[11];
    float p = h_t * wgate[lane];
#pragma unroll
    for (int d = 1; d < 64; d <<= 1) p += __shfl_xor(p, d);
    const float gate = 1.f / (1.f + expf(-(p + bgate[0])));
    const float fo = gate * h_t + (1.f - gate) * h_s;
    xls[lane] = fo;
    if (lane < 12) {
        float acc = bout[lane];
#pragma unroll
        for (int o = 0; o < 64; ++o)
            acc = fmaf(xls[o], wout[o * 12 + lane], acc);
        outp[lane * 8000 + b * 2000 + n] = acc;
    }
}

extern "C" void kernel_launch(void* const* d_in, const int* in_sizes, int n_in,
                              void* d_out, int out_size, void* d_ws, size_t ws_size,
                              hipStream_t stream) {
    const float* inputs     = (const float*)d_in[0];
    const float* node_feas  = (const float*)d_in[1];
    const int*   node_index = (const int*)  d_in[2];
    const float* w_fc3 = (const float*)d_in[3];
    const float* b_fc3 = (const float*)d_in[4];
    const float* w_fc4 = (const float*)d_in[5];
    const float* b_fc4 = (const float*)d_in[6];
    const float* w_fc5 = (const float*)d_in[7];
    const float* b_fc5 = (const float*)d_in[8];
    const float* w_nhp = (const float*)d_in[9];
    const float* b_nhp = (const float*)d_in[10];
    const float* w_q   = (const float*)d_in[11];
    const float* w_k   = (const float*)d_in[12];
    const float* w_in  = (const float*)d_in[13];
    const float* b_in  = (const float*)d_in[14];
    const float* sws   = (const float*)d_in[15];
    const float* sbs   = (const float*)d_in[16];
    const float* swn   = (const float*)d_in[17];
    const float* sbn   = (const float*)d_in[18];
    const float* tw1   = (const float*)d_in[19];
    const float* tb1   = (const float*)d_in[20];
    const float* tw2   = (const float*)d_in[21];
    const float* tb2   = (const float*)d_in[22];
    const float* wgate = (const float*)d_in[23];
    const float* bgate = (const float*)d_in[24];
    const float* wout  = (const float*)d_in[25];
    const float* bout  = (const float*)d_in[26];

    float* out  = (float*)d_out;           // (12,4,2000)        96000
    float* mid  = out + 96000;             // (4,12,2000,64)     6144000
    float* wadj = mid + 6144000;           // (2000,32)          64000

    float*  q     = (float*)d_ws;          // 128000
    float*  ek    = q     + 128000;        // 128000
    float*  nh2   = ek    + 128000;        // 128000 (includes b_nhp + b_in)
    float*  base1 = nh2   + 128000;        // 128000
    float*  xT    = base1 + 128000;        // 96000   [n][bt]
    float2* xa    = (float2*)(xT + 96000); // 96000 float2 {x, ax}
    float*  vecs  = xT + 96000 + 192000;   // 128 {s1v, n1v}

    k_embed<<<500, 256, 0, stream>>>(node_feas, inputs, w_fc3, b_fc3, w_fc4, b_fc4,
                                     w_fc5, b_fc5, w_q, w_k, w_nhp, b_nhp, b_in,
                                     q, ek, nh2, xT);
    k_scores<<<250, 256, 0, stream>>>(q, ek, node_index, wadj);
    k_ax<<<500, 256, 0, stream>>>(xT, node_index, wadj, xa);
    k_prep<<<501, 256, 0, stream>>>(nh2, node_index, wadj, sws, sbs, swn, sbn,
                                    w_in, base1, vecs);
    k_sage2<<<2000, 512, 0, stream>>>(base1, xa, vecs, node_index, wadj,
                                      sws, sbs, swn, sbn, mid);
    dim3 gt(500, 4);
    k_tcn<<<gt, 256, 0, stream>>>(mid, tw1, tb1, tw2, tb2,
                                  wgate, bgate, wout, bout, out);
}

// Round 3
// 198.941 us; speedup vs baseline: 2.3673x; 1.0814x over previous
//
#include <hip/hip_runtime.h>
#include <math.h>

// Sizes: N=2000, M=32, H=64, EMB=32, F=32, T=12, B=4, HOR=12, K=2, DILS=(1,2)

// ---------------- K1: node MLP -> q, ek, nh2 (= e@w_nhp + b_nhp + b_in); also xT ----
__global__ __launch_bounds__(256) void k_embed(
    const float* __restrict__ nf, const float* __restrict__ inputs,
    const float* __restrict__ w3, const float* __restrict__ b3,
    const float* __restrict__ w4, const float* __restrict__ b4,
    const float* __restrict__ w5, const float* __restrict__ b5,
    const float* __restrict__ wq, const float* __restrict__ wk,
    const float* __restrict__ wn, const float* __restrict__ bn,
    const float* __restrict__ b_in,
    float* __restrict__ qo, float* __restrict__ eko, float* __restrict__ nho,
    float* __restrict__ xT)
{
    const int tid = threadIdx.x;
    if (tid < 192) {                                   // xT transpose: 500*192 = 96000
        const int id = blockIdx.x * 192 + tid;
        const int t = id / 8000, rem = id % 8000;
        const int b = rem / 2000, n2 = rem % 2000;
        xT[n2 * 48 + b * 12 + t] = inputs[id];
    }
    const int lane = tid & 63;
    const int n = blockIdx.x * 4 + (tid >> 6);

    float nfv = 0.f;
    if (lane < 32) nfv = nf[n * 32 + lane];

    float e1 = b3[lane];
#pragma unroll
    for (int f = 0; f < 32; ++f)
        e1 = fmaf(__shfl(nfv, f), w3[f * 64 + lane], e1);
    e1 = fmaxf(e1, 0.f);

    float e2 = b4[lane];
#pragma unroll
    for (int f = 0; f < 64; ++f)
        e2 = fmaf(__shfl(e1, f), w4[f * 64 + lane], e2);
    e2 = fmaxf(e2, 0.f);

    const int c = lane & 31;
    float ev = b5[c];
#pragma unroll
    for (int f = 0; f < 64; ++f)
        ev = fmaf(__shfl(e2, f), w5[f * 32 + c], ev);

    float qv = 0.f, ekv = 0.f, nhv = bn[lane] + b_in[lane];
#pragma unroll
    for (int f = 0; f < 32; ++f) {
        float e = __shfl(ev, f);
        qv  = fmaf(e, wq[f * 64 + lane], qv);
        ekv = fmaf(e, wk[f * 64 + lane], ekv);
        nhv = fmaf(e, wn[f * 64 + lane], nhv);
    }
    qo [n * 64 + lane] = qv;
    eko[n * 64 + lane] = ekv;
    nho[n * 64 + lane] = nhv;
}

// ---------------- K2: attention scores + softmax -> w_adj ----------
__global__ __launch_bounds__(256) void k_scores(
    const float* __restrict__ q, const float* __restrict__ ek,
    const int* __restrict__ nidx, float* __restrict__ wadj)
{
    const int tid = threadIdx.x;
    const int m = tid & 31;
    const int n = blockIdx.x * 8 + (tid >> 5);
    const int j = nidx[n * 32 + m];
    const float4* qr = (const float4*)(q + n * 64);
    const float4* er = (const float4*)(ek + j * 64);
    float s = 0.f;
#pragma unroll
    for (int u = 0; u < 16; ++u) {
        float4 a = qr[u], b = er[u];
        s = fmaf(a.x, b.x, s); s = fmaf(a.y, b.y, s);
        s = fmaf(a.z, b.z, s); s = fmaf(a.w, b.w, s);
    }
    s *= 0.125f;
    float mx = s;
#pragma unroll
    for (int d = 16; d >= 1; d >>= 1) mx = fmaxf(mx, __shfl_xor(mx, d));
    const float ex = expf(s - mx);
    float sum = ex;
#pragma unroll
    for (int d = 16; d >= 1; d >>= 1) sum += __shfl_xor(sum, d);
    wadj[n * 32 + m] = ex / sum;
}

// ---------------- K3: ax[n][bt] = sum_m w[n,m] * x[bt, j_m];  pack xa = {x_self, ax} ----
__global__ __launch_bounds__(256) void k_ax(
    const float* __restrict__ xT, const int* __restrict__ nidx,
    const float* __restrict__ wadj, float2* __restrict__ xa)
{
    const int lane = threadIdx.x & 63, wave = threadIdx.x >> 6;
    const int n = blockIdx.x * 4 + wave;
    int j = 0; float w = 0.f;
    if (lane < 32) { j = nidx[n * 32 + lane]; w = wadj[n * 32 + lane]; }
    const bool act = lane < 48;
    float ax = 0.f;
#pragma unroll
    for (int m = 0; m < 32; ++m) {
        const int jm = __shfl(j, m);
        const float wm = __shfl(w, m);
        const float xv = act ? xT[jm * 48 + lane] : 0.f;
        ax = fmaf(wm, xv, ax);
    }
    if (act) xa[n * 48 + lane] = make_float2(xT[n * 48 + lane], ax);
}

// ---------------- K3b: base1[n] = nh2[n]@Ws1 + (A nh2)[n]@Wn1 + b1 ; block 500: vecs ----
__global__ __launch_bounds__(256) void k_prep(
    const float* __restrict__ nh2, const int* __restrict__ nidx,
    const float* __restrict__ wadj,
    const float* __restrict__ sws, const float* __restrict__ sbs,
    const float* __restrict__ swn, const float* __restrict__ sbn,
    const float* __restrict__ w_in,
    float* __restrict__ base1, float* __restrict__ vecs)
{
    const int tid = threadIdx.x;
    const int lane = tid & 63, wave = tid >> 6;
    if (blockIdx.x == 500) {                      // s1v = w_in@Ws1, n1v = w_in@Wn1
        if (wave == 0) {
            const float wv = w_in[lane];
            float s1 = 0.f, n1 = 0.f;
#pragma unroll
            for (int k = 0; k < 64; ++k) {
                const float wkk = __shfl(wv, k);
                s1 = fmaf(wkk, sws[k * 64 + lane], s1);
                n1 = fmaf(wkk, swn[k * 64 + lane], n1);
            }
            vecs[lane] = s1; vecs[64 + lane] = n1;
        }
        return;
    }
    __shared__ float2 sw1[4096];
    __shared__ float2 sv1[4][64];
    for (int u = tid; u < 4096; u += 256)
        sw1[u] = make_float2(sws[u], swn[u]);
    __syncthreads();
    const int n = blockIdx.x * 4 + wave;
    int jv = 0; float wv = 0.f;
    if (lane < 32) { jv = nidx[n * 32 + lane]; wv = wadj[n * 32 + lane]; }
    const float self = nh2[n * 64 + lane];
    float anh = 0.f;
#pragma unroll
    for (int m = 0; m < 32; ++m) {
        const int jm = __shfl(jv, m);
        const float wm = __shfl(wv, m);
        anh = fmaf(wm, nh2[jm * 64 + lane], anh);
    }
    sv1[wave][lane] = make_float2(self, anh);
    float acc = sbs[lane] + sbn[lane];
#pragma unroll
    for (int k = 0; k < 64; ++k) {
        const float2 sa = sv1[wave][k];            // broadcast
        const float2 w2 = sw1[k * 64 + lane];
        acc = fmaf(sa.x, w2.x, fmaf(sa.y, w2.y, acc));
    }
    base1[n * 64 + lane] = acc;
}

// ---------------- K4: fused SAGE layer 2 (recompute h1 from scalars) -> mid ----------
__global__ __launch_bounds__(512, 4) void k_sage2(
    const float* __restrict__ base1, const float2* __restrict__ xa,
    const float* __restrict__ vecs,
    const int* __restrict__ nidx, const float* __restrict__ wadj,
    const float* __restrict__ sws, const float* __restrict__ sbs,
    const float* __restrict__ swn, const float* __restrict__ sbn,
    float* __restrict__ mid)
{
    __shared__ float2 sw2[4096];                  // {Ws2,Wn2}[k*64+h], 32 KB
    __shared__ float2 sv[48][64];                 // {h1self, agg}[bt][k], 24 KB
    __shared__ int2 jwl[32];                      // {j, bits(w)}
    const int tid = threadIdx.x, lane = tid & 63, wave = tid >> 6;
    const int n = blockIdx.x;
    if (tid < 32)
        jwl[tid] = make_int2(nidx[n * 32 + tid], __float_as_int(wadj[n * 32 + tid]));
    for (int u = tid; u < 4096; u += 512)
        sw2[u] = make_float2(sws[4096 + u], swn[4096 + u]);
    __syncthreads();

    const float s1 = vecs[lane], n1 = vecs[64 + lane];
    const float bs = base1[n * 64 + lane];
    const float b2 = sbs[64 + lane] + sbn[64 + lane];
    const int bt0 = wave * 6;

    float agg[6] = {0.f, 0.f, 0.f, 0.f, 0.f, 0.f};
#pragma unroll 8
    for (int m = 0; m < 32; ++m) {
        const int2 jw = jwl[m];
        const int j = jw.x;
        const float w = __int_as_float(jw.y);
        const float bj = base1[j * 64 + lane];
        const float2* xr = xa + j * 48 + bt0;
#pragma unroll
        for (int r = 0; r < 6; ++r) {
            const float2 v = xr[r];
            const float t = fmaf(v.x, s1, fmaf(v.y, n1, bj));
            agg[r] = fmaf(w, fmaxf(t, 0.f), agg[r]);
        }
    }
#pragma unroll
    for (int r = 0; r < 6; ++r) {
        const float2 v = xa[n * 48 + bt0 + r];
        const float h1s = fmaxf(fmaf(v.x, s1, fmaf(v.y, n1, bs)), 0.f);
        sv[bt0 + r][lane] = make_float2(h1s, agg[r]);
    }
    float acc[6];
#pragma unroll
    for (int r = 0; r < 6; ++r) acc[r] = b2;
#pragma unroll
    for (int k = 0; k < 64; ++k) {
        const float2 w2 = sw2[k * 64 + lane];
#pragma unroll
        for (int r = 0; r < 6; ++r) {
            const float2 ha = sv[bt0 + r][k];
            acc[r] = fmaf(ha.x, w2.x, fmaf(ha.y, w2.y, acc[r]));
        }
    }
#pragma unroll
    for (int r = 0; r < 6; ++r)
        mid[((bt0 + r) * 2000 + n) * 64 + lane] = fmaxf(acc[r], 0.f);
}

// ---------------- K5: TCN (2 layers x 2 causal convs, K=2) + head ----------
// 512-thread blocks, 8 waves, each wave owns TWO sequences. Weights staged
// once per conv for the whole block (32 KB LDS); per-wave x buffers (2x3 KB).
template<int D>
__device__ __forceinline__ void conv2_k2(const float* x0, const float* x1,
                                         const float* wls, float bias,
                                         float* a0, float* a1, int lane)
{
#pragma unroll
    for (int t = 0; t < 12; ++t) { a0[t] = bias; a1[t] = bias; }
#pragma unroll 8
    for (int i = 0; i < 64; ++i) {
        const float2 w2 = *(const float2*)(wls + (i * 64 + lane) * 2);
        const float4 p0 = *(const float4*)(x0 + i * 12);
        const float4 p1 = *(const float4*)(x0 + i * 12 + 4);
        const float4 p2 = *(const float4*)(x0 + i * 12 + 8);
        const float4 q0 = *(const float4*)(x1 + i * 12);
        const float4 q1 = *(const float4*)(x1 + i * 12 + 4);
        const float4 q2 = *(const float4*)(x1 + i * 12 + 8);
        const float xv0[12] = {p0.x,p0.y,p0.z,p0.w, p1.x,p1.y,p1.z,p1.w,
                               p2.x,p2.y,p2.z,p2.w};
        const float xv1[12] = {q0.x,q0.y,q0.z,q0.w, q1.x,q1.y,q1.z,q1.w,
                               q2.x,q2.y,q2.z,q2.w};
#pragma unroll
        for (int t = 0; t < 12; ++t) {
            float s0 = fmaf(w2.y, xv0[t], a0[t]);
            float s1 = fmaf(w2.y, xv1[t], a1[t]);
            if (t >= D) {
                s0 = fmaf(w2.x, xv0[t - D], s0);
                s1 = fmaf(w2.x, xv1[t - D], s1);
            }
            a0[t] = s0; a1[t] = s1;
        }
    }
#pragma unroll
    for (int t = 0; t < 12; ++t) {
        a0[t] = fmaxf(a0[t], 0.f);
        a1[t] = fmaxf(a1[t], 0.f);
    }
}

__device__ __forceinline__ void store12(float* xls, const float* v, int lane)
{
#pragma unroll
    for (int j = 0; j < 3; ++j)
        *(float4*)(xls + lane * 12 + j * 4) =
            make_float4(v[j*4], v[j*4+1], v[j*4+2], v[j*4+3]);
}

template<int D>
__device__ __forceinline__ void tcn_layer2(float* x0, float* x1, float* wls,
    int tid, int lane,
    const float* W1, const float* B1, const float* W2, const float* B2,
    float* r0, float* r1)
{
    __syncthreads();   // all waves done reading previous wls contents
    for (int u = tid; u < 4096; u += 512)
        *(float2*)(wls + u * 2) = *(const float2*)(W1 + ((u & 63) * 128 + (u >> 6) * 2));
    __syncthreads();
    float y0[12], y1[12];
    conv2_k2<D>(x0, x1, wls, B1[lane], y0, y1, lane);
    store12(x0, y0, lane);
    store12(x1, y1, lane);
    __syncthreads();
    for (int u = tid; u < 4096; u += 512)
        *(float2*)(wls + u * 2) = *(const float2*)(W2 + ((u & 63) * 128 + (u >> 6) * 2));
    __syncthreads();
    conv2_k2<D>(x0, x1, wls, B2[lane], y0, y1, lane);
#pragma unroll
    for (int t = 0; t < 12; ++t) {
        r0[t] = fmaxf(y0[t] + r0[t], 0.f);
        r1[t] = fmaxf(y1[t] + r1[t], 0.f);
    }
    store12(x0, r0, lane);
    store12(x1, r1, lane);
}

__global__ __launch_bounds__(512, 4) void k_tcn(
    const float* __restrict__ mid,
    const float* __restrict__ tw1, const float* __restrict__ tb1,
    const float* __restrict__ tw2, const float* __restrict__ tb2,
    const float* __restrict__ wgate, const float* __restrict__ bgate,
    const float* __restrict__ wout, const float* __restrict__ bout,
    float* __restrict__ outp)
{
    __shared__ __align__(16) float xls_all[8][2][768];   // 48 KB
    __shared__ __align__(16) float wls[8192];            // 32 KB
    const int tid = threadIdx.x, lane = tid & 63, wave = tid >> 6;
    const int seq0 = (blockIdx.x * 8 + wave) * 2;        // 500 blocks * 8 waves * 2
    const int b = seq0 / 2000, n0 = seq0 % 2000;         // n0 even, n1 = n0+1 same b
    float* x0 = xls_all[wave][0];
    float* x1 = xls_all[wave][1];

    float r0[12], r1[12];
#pragma unroll
    for (int t = 0; t < 12; ++t) {
        r0[t] = mid[((b * 12 + t) * 2000 + n0) * 64 + lane];
        r1[t] = mid[((b * 12 + t) * 2000 + n0 + 1) * 64 + lane];
    }
    store12(x0, r0, lane);
    store12(x1, r1, lane);
    const float hs0 = r0[11], hs1 = r1[11];              // mid_output[:, -1]

    tcn_layer2<1>(x0, x1, wls, tid, lane, tw1,        tb1,      tw2,        tb2,      r0, r1);
    tcn_layer2<2>(x0, x1, wls, tid, lane, tw1 + 8192, tb1 + 64, tw2 + 8192, tb2 + 64, r0, r1);

    const float wg = wgate[lane];
    const float ht0 = r0[11], ht1 = r1[11];
    float p0 = ht0 * wg, p1 = ht1 * wg;
#pragma unroll
    for (int d = 1; d < 64; d <<= 1) {
        p0 += __shfl_xor(p0, d);
        p1 += __shfl_xor(p1, d);
    }
    const float g0 = 1.f / (1.f + expf(-(p0 + bgate[0])));
    const float g1 = 1.f / (1.f + expf(-(p1 + bgate[0])));
    const float fo0 = g0 * ht0 + (1.f - g0) * hs0;
    const float fo1 = g1 * ht1 + (1.f - g1) * hs1;
    x0[lane] = fo0;
    x1[lane] = fo1;
    if (lane < 24) {
        const int s = lane >= 12;                        // 0: seq0, 1: seq1
        const int o = lane - s * 12;
        const float* xs = s ? x1 : x0;
        float acc = bout[o];
#pragma unroll
        for (int k = 0; k < 64; ++k)
            acc = fmaf(xs[k], wout[k * 12 + o], acc);
        outp[o * 8000 + b * 2000 + n0 + s] = acc;
    }
}

extern "C" void kernel_launch(void* const* d_in, const int* in_sizes, int n_in,
                              void* d_out, int out_size, void* d_ws, size_t ws_size,
                              hipStream_t stream) {
    const float* inputs     = (const float*)d_in[0];
    const float* node_feas  = (const float*)d_in[1];
    const int*   node_index = (const int*)  d_in[2];
    const float* w_fc3 = (const float*)d_in[3];
    const float* b_fc3 = (const float*)d_in[4];
    const float* w_fc4 = (const float*)d_in[5];
    const float* b_fc4 = (const float*)d_in[6];
    const float* w_fc5 = (const float*)d_in[7];
    const float* b_fc5 = (const float*)d_in[8];
    const float* w_nhp = (const float*)d_in[9];
    const float* b_nhp = (const float*)d_in[10];
    const float* w_q   = (const float*)d_in[11];
    const float* w_k   = (const float*)d_in[12];
    const float* w_in  = (const float*)d_in[13];
    const float* b_in  = (const float*)d_in[14];
    const float* sws   = (const float*)d_in[15];
    const float* sbs   = (const float*)d_in[16];
    const float* swn   = (const float*)d_in[17];
    const float* sbn   = (const float*)d_in[18];
    const float* tw1   = (const float*)d_in[19];
    const float* tb1   = (const float*)d_in[20];
    const float* tw2   = (const float*)d_in[21];
    const float* tb2   = (const float*)d_in[22];
    const float* wgate = (const float*)d_in[23];
    const float* bgate = (const float*)d_in[24];
    const float* wout  = (const float*)d_in[25];
    const float* bout  = (const float*)d_in[26];

    float* out  = (float*)d_out;           // (12,4,2000)        96000
    float* mid  = out + 96000;             // (4,12,2000,64)     6144000
    float* wadj = mid + 6144000;           // (2000,32)          64000

    float*  q     = (float*)d_ws;          // 128000
    float*  ek    = q     + 128000;        // 128000
    float*  nh2   = ek    + 128000;        // 128000 (includes b_nhp + b_in)
    float*  base1 = nh2   + 128000;        // 128000
    float*  xT    = base1 + 128000;        // 96000   [n][bt]
    float2* xa    = (float2*)(xT + 96000); // 96000 float2 {x, ax}
    float*  vecs  = xT + 96000 + 192000;   // 128 {s1v, n1v}

    k_embed<<<500, 256, 0, stream>>>(node_feas, inputs, w_fc3, b_fc3, w_fc4, b_fc4,
                                     w_fc5, b_fc5, w_q, w_k, w_nhp, b_nhp, b_in,
                                     q, ek, nh2, xT);
    k_scores<<<250, 256, 0, stream>>>(q, ek, node_index, wadj);
    k_ax<<<500, 256, 0, stream>>>(xT, node_index, wadj, xa);
    k_prep<<<501, 256, 0, stream>>>(nh2, node_index, wadj, sws, sbs, swn, sbn,
                                    w_in, base1, vecs);
    k_sage2<<<2000, 512, 0, stream>>>(base1, xa, vecs, node_index, wadj,
                                      sws, sbs, swn, sbn, mid);
    k_tcn<<<500, 512, 0, stream>>>(mid, tw1, tb1, tw2, tb2,
                                   wgate, bgate, wout, bout, out);
}